// Round 2
// baseline (416.693 us; speedup 1.0000x reference)
//
#include <hip/hip_runtime.h>
#include <stdint.h>

#define B_N 4096
#define T_N 17
#define C_N 512

typedef __bf16 bf16x8 __attribute__((ext_vector_type(8)));
typedef float  f32x4  __attribute__((ext_vector_type(4)));

// fp32 -> bf16, round-to-nearest-even (values are finite; no NaN path needed)
__device__ __forceinline__ unsigned short f2b(float f){
  unsigned u = __float_as_uint(f);
  return (unsigned short)((u + 0x7fffu + ((u >> 16) & 1u)) >> 16);
}
__device__ __forceinline__ unsigned pk2(float a, float b){
  return (unsigned)f2b(a) | ((unsigned)f2b(b) << 16);
}
__device__ __forceinline__ float blo(unsigned w){ return __uint_as_float(w << 16); }
__device__ __forceinline__ float bhi(unsigned w){ return __uint_as_float(w & 0xffff0000u); }

// async global->LDS, 16B/lane; LDS dest = wave-uniform base + lane*16 (lanes'
// pointers ARE base+lane*16 here: chunk = r*256+tid is lane-consecutive per wave)
__device__ __forceinline__ void gll16(const void* g, void* l){
  __builtin_amdgcn_global_load_lds(
      (const __attribute__((address_space(1))) unsigned int*)g,
      (__attribute__((address_space(3))) unsigned int*)l, 16, 0, 0);
}

// ---------------------------------------------------------------------------
// prep_w: Ws_bf = bf16(Ws), dW_bf = bf16(Wt - Ws).  17*512*512/8 = 557056 thr.
// ---------------------------------------------------------------------------
__global__ __launch_bounds__(256) void prep_w(
    const float* __restrict__ Ws, const float* __restrict__ Wt,
    unsigned short* __restrict__ wsb, unsigned short* __restrict__ dwb)
{
  const size_t i8 = ((size_t)blockIdx.x * 256 + threadIdx.x) * 8;
  float4 a0 = *(const float4*)(Ws + i8);
  float4 a1 = *(const float4*)(Ws + i8 + 4);
  float4 b0 = *(const float4*)(Wt + i8);
  float4 b1 = *(const float4*)(Wt + i8 + 4);
  uint4 oa, od;
  oa.x = pk2(a0.x, a0.y); oa.y = pk2(a0.z, a0.w);
  oa.z = pk2(a1.x, a1.y); oa.w = pk2(a1.z, a1.w);
  od.x = pk2(b0.x - a0.x, b0.y - a0.y); od.y = pk2(b0.z - a0.z, b0.w - a0.w);
  od.z = pk2(b1.x - a1.x, b1.y - a1.y); od.w = pk2(b1.z - a1.z, b1.w - a1.w);
  *(uint4*)(wsb + i8) = oa;
  *(uint4*)(dwb + i8) = od;
}

// bsum = bs + bt (fp32), 17*512 = 8704 elems
__global__ __launch_bounds__(256) void prep_bsum(
    const float* __restrict__ bs, const float* __restrict__ bt, float* __restrict__ o)
{
  const int i = blockIdx.x * 256 + threadIdx.x;
  o[i] = bs[i] + bt[i];
}

// ---------------------------------------------------------------------------
// prep_x: one pass over x (fp32). trend[b,t,c] = u + t*v with
//   u = (S + 18*x0 + 2*x16)/37, v = (x16 - x0)/37, S = sum_t x[b,t,c]
// MAT: write x_bf [B,T,C] and trend_bf [B,T,C]. !MAT: write u,v planes [B,C].
// ---------------------------------------------------------------------------
template<bool MAT>
__global__ __launch_bounds__(256) void prep_x(
    const float* __restrict__ x,
    unsigned short* __restrict__ o1,   // MAT: x_bf ; !MAT: u
    unsigned short* __restrict__ o2)   // MAT: trend; !MAT: v
{
  const int idx = blockIdx.x * 256 + threadIdx.x;   // B_N * C_N/8 = 262144
  const int b = idx >> 6;
  const int c = (idx & 63) << 3;
  const float* xp = x + (size_t)b * (T_N * C_N) + c;
  float s[8] = {0,0,0,0,0,0,0,0};
  float f0[8], fl[8];
#pragma unroll
  for (int tt = 0; tt < T_N; ++tt){
    float4 w0 = *(const float4*)(xp + (size_t)tt * C_N);
    float4 w1 = *(const float4*)(xp + (size_t)tt * C_N + 4);
    float f[8] = {w0.x, w0.y, w0.z, w0.w, w1.x, w1.y, w1.z, w1.w};
    if (MAT){
      uint4 o;
      o.x = pk2(f[0],f[1]); o.y = pk2(f[2],f[3]);
      o.z = pk2(f[4],f[5]); o.w = pk2(f[6],f[7]);
      *(uint4*)(o1 + (size_t)b * (T_N*C_N) + (size_t)tt * C_N + c) = o;
    }
    if (tt == 0){
#pragma unroll
      for (int i=0;i<8;++i) f0[i] = f[i];
    }
    if (tt == T_N-1){
#pragma unroll
      for (int i=0;i<8;++i) fl[i] = f[i];
    }
#pragma unroll
    for (int i=0;i<8;++i) s[i] += f[i];
  }
  const float inv = 1.0f / 37.0f;
  float uu[8], vv[8];
#pragma unroll
  for (int i=0;i<8;++i){
    uu[i] = (s[i] + 18.0f * f0[i] + 2.0f * fl[i]) * inv;
    vv[i] = (fl[i] - f0[i]) * inv;
  }
  if (MAT){
#pragma unroll
    for (int tt = 0; tt < T_N; ++tt){
      const float tfv = (float)tt;
      float tr[8];
#pragma unroll
      for (int i=0;i<8;++i) tr[i] = fmaf(tfv, vv[i], uu[i]);
      uint4 o;
      o.x = pk2(tr[0],tr[1]); o.y = pk2(tr[2],tr[3]);
      o.z = pk2(tr[4],tr[5]); o.w = pk2(tr[6],tr[7]);
      *(uint4*)(o2 + (size_t)b * (T_N*C_N) + (size_t)tt * C_N + c) = o;
    }
  } else {
    uint4 ou, ov;
    ou.x = pk2(uu[0],uu[1]); ou.y = pk2(uu[2],uu[3]);
    ou.z = pk2(uu[4],uu[5]); ou.w = pk2(uu[6],uu[7]);
    ov.x = pk2(vv[0],vv[1]); ov.y = pk2(vv[2],vv[3]);
    ov.z = pk2(vv[4],vv[5]); ov.w = pk2(vv[6],vv[7]);
    *(uint4*)(o1 + (size_t)b * C_N + c) = ou;
    *(uint4*)(o2 + (size_t)b * C_N + c) = ov;
  }
}

// ---------------------------------------------------------------------------
// gemm: per token t, out[:,t,:] = [x | trend]_bf (M=4096 x K=1024) *
//       [Ws | dW]_bf^T + bsum, fp32 accumulate/store.
// 128x128 tile, BK=32, 4 waves, 4x4 frags of mfma_f32_16x16x32_bf16.
// LDS tiles [128 rows][32 k] bf16; 16B chunks XOR-swizzled: slot s of row r
// holds global chunk s ^ ((r>>1)&3) -> free 2-way bank aliasing on ds_read_b128.
// ---------------------------------------------------------------------------
template<bool MAT>
__global__ __launch_bounds__(256) void gemm_k(
    const float* __restrict__ x,            // fp32 x (used when !MAT, k<512)
    const unsigned short* __restrict__ xb,  // MAT: x_bf
    const unsigned short* __restrict__ wsb, // Ws bf16
    const unsigned short* __restrict__ dwb, // dW bf16
    const unsigned short* __restrict__ p1,  // MAT: trend_bf ; !MAT: u
    const unsigned short* __restrict__ p2,  // !MAT: v
    const float* __restrict__ bsum,
    float* __restrict__ out)
{
  __shared__ alignas(16) unsigned short As[128*32];
  __shared__ alignas(16) unsigned short Bs[128*32];

  const int tid  = threadIdx.x;
  const int bx   = blockIdx.x;          // 0..2175 = t*128 + mt*4 + nt
  const int nt   = bx & 3;
  const int mt   = (bx >> 2) & 31;
  const int t    = bx >> 7;
  const int m0   = mt << 7;
  const int n0   = nt << 7;
  const int lane = tid & 63;
  const int wave = tid >> 6;
  const int wm   = (wave >> 1) << 6;
  const int wn   = (wave & 1) << 6;
  const int lr   = lane & 15;
  const int lj   = lane >> 4;           // k-chunk group 0..3
  const int swz  = (lr >> 1) & 3;       // == (row>>1)&3 for fragment rows

  f32x4 acc[4][4];
#pragma unroll
  for (int i=0;i<4;++i)
#pragma unroll
    for (int j=0;j<4;++j){ f32x4 z = {0.f,0.f,0.f,0.f}; acc[i][j] = z; }

  const float tf = (float)t;

  for (int kk = 0; kk < 32; ++kk){
    const int k0 = kk << 5;
    __syncthreads();
    // ---- stage A tile (rows = batch) ----
    if (MAT){
#pragma unroll
      for (int r = 0; r < 2; ++r){
        const int chunk = r*256 + tid;              // 16B chunk id, 0..511
        const int row = chunk >> 2;
        const int cgl = (chunk & 3) ^ ((row >> 1) & 3);
        const unsigned short* g = (k0 < 512)
          ? xb + ((size_t)(m0+row)*T_N + t)*C_N + k0 + cgl*8
          : p1 + ((size_t)(m0+row)*T_N + t)*C_N + (k0 - 512) + cgl*8;
        gll16(g, &As[chunk*8]);
      }
    } else if (k0 < 512){
      // convert fp32 x -> bf16 on the fly
#pragma unroll
      for (int r = 0; r < 2; ++r){
        const int chunk = r*256 + tid;
        const int row = chunk >> 2;
        const int cgl = (chunk & 3) ^ ((row >> 1) & 3);
        const float* g = x + ((size_t)(m0+row)*T_N + t)*C_N + k0 + cgl*8;
        float4 w0 = *(const float4*)g;
        float4 w1 = *(const float4*)(g + 4);
        uint4 o;
        o.x = pk2(w0.x, w0.y); o.y = pk2(w0.z, w0.w);
        o.z = pk2(w1.x, w1.y); o.w = pk2(w1.z, w1.w);
        *(uint4*)&As[chunk*8] = o;
      }
    } else {
      // trend = u + t*v from bf16 planes
#pragma unroll
      for (int r = 0; r < 2; ++r){
        const int chunk = r*256 + tid;
        const int row = chunk >> 2;
        const int cgl = (chunk & 3) ^ ((row >> 1) & 3);
        const size_t go = (size_t)(m0+row)*C_N + (k0 - 512) + cgl*8;
        uint4 uu = *(const uint4*)(p1 + go);
        uint4 vv = *(const uint4*)(p2 + go);
        uint4 o;
        o.x = pk2(fmaf(tf, blo(vv.x), blo(uu.x)), fmaf(tf, bhi(vv.x), bhi(uu.x)));
        o.y = pk2(fmaf(tf, blo(vv.y), blo(uu.y)), fmaf(tf, bhi(vv.y), bhi(uu.y)));
        o.z = pk2(fmaf(tf, blo(vv.z), blo(uu.z)), fmaf(tf, bhi(vv.z), bhi(uu.z)));
        o.w = pk2(fmaf(tf, blo(vv.w), blo(uu.w)), fmaf(tf, bhi(vv.w), bhi(uu.w)));
        *(uint4*)&As[chunk*8] = o;
      }
    }
    // ---- stage B tile (rows = output channel d) ----
#pragma unroll
    for (int r = 0; r < 2; ++r){
      const int chunk = r*256 + tid;
      const int row = chunk >> 2;
      const int cgl = (chunk & 3) ^ ((row >> 1) & 3);
      const unsigned short* g = (k0 < 512)
        ? wsb + ((size_t)t*C_N + n0 + row)*C_N + k0 + cgl*8
        : dwb + ((size_t)t*C_N + n0 + row)*C_N + (k0 - 512) + cgl*8;
      gll16(g, &Bs[chunk*8]);
    }
    __syncthreads();

    bf16x8 af[4], bf[4];
#pragma unroll
    for (int i=0;i<4;++i){
      const int row = wm + i*16 + lr;          // A: m = lane&15 (+16*i +wm)
      af[i] = *(const bf16x8*)&As[row*32 + ((lj ^ swz) * 8)];
    }
#pragma unroll
    for (int i=0;i<4;++i){
      const int row = wn + i*16 + lr;          // B: n = lane&15 (+16*i +wn)
      bf[i] = *(const bf16x8*)&Bs[row*32 + ((lj ^ swz) * 8)];
    }
#pragma unroll
    for (int mi=0;mi<4;++mi)
#pragma unroll
      for (int ni=0;ni<4;++ni)
        acc[mi][ni] = __builtin_amdgcn_mfma_f32_16x16x32_bf16(af[mi], bf[ni], acc[mi][ni], 0, 0, 0);
  }

  // ---- epilogue: + (bs+bt), fp32 store.  C/D: col=lane&15, row=(lane>>4)*4+reg ----
  float bias[4];
#pragma unroll
  for (int ni=0;ni<4;++ni)
    bias[ni] = bsum[(size_t)t*C_N + n0 + wn + ni*16 + lr];

#pragma unroll
  for (int mi=0;mi<4;++mi){
#pragma unroll
    for (int r=0;r<4;++r){
      const int m = m0 + wm + mi*16 + lj*4 + r;
      float* op = out + ((size_t)m*T_N + t)*C_N + n0 + wn + lr;
#pragma unroll
      for (int ni=0;ni<4;++ni)
        op[ni*16] = acc[mi][ni][r] + bias[ni];
    }
  }
}

extern "C" void kernel_launch(void* const* d_in, const int* in_sizes, int n_in,
                              void* d_out, int out_size, void* d_ws, size_t ws_size,
                              hipStream_t stream)
{
  const float* x   = (const float*)d_in[0];
  const float* Wsl = (const float*)d_in[1];
  const float* bsl = (const float*)d_in[2];
  const float* Wtr = (const float*)d_in[3];
  const float* btr = (const float*)d_in[4];
  float* out = (float*)d_out;

  const size_t WSB_BYTES = (size_t)T_N*C_N*C_N*2;  // 8,912,896
  const size_t DW_BYTES  = WSB_BYTES;              // 8,912,896
  const size_t BS_BYTES  = (size_t)T_N*C_N*4;      // 34,816
  const size_t XB_BYTES  = (size_t)B_N*T_N*C_N*2;  // 71,303,168
  const size_t TR_BYTES  = XB_BYTES;               // 71,303,168
  const size_t UV_BYTES  = (size_t)B_N*C_N*2;      // 4,194,304

  char* ws = (char*)d_ws;
  unsigned short* wsb  = (unsigned short*)ws;
  unsigned short* dwb  = (unsigned short*)(ws + WSB_BYTES);
  float*          bsum = (float*)(ws + WSB_BYTES + DW_BYTES);
  char* rest = ws + WSB_BYTES + DW_BYTES + BS_BYTES;
  // fixed per run (ws_size constant) -> graph-capture safe
  const bool mat = ws_size >= WSB_BYTES + DW_BYTES + BS_BYTES + XB_BYTES + TR_BYTES;

  prep_w<<<dim3(2176), dim3(256), 0, stream>>>(Wsl, Wtr, wsb, dwb);
  prep_bsum<<<dim3(34), dim3(256), 0, stream>>>(bsl, btr, bsum);
  if (mat){
    unsigned short* xb    = (unsigned short*)rest;
    unsigned short* trend = (unsigned short*)(rest + XB_BYTES);
    prep_x<true><<<dim3(1024), dim3(256), 0, stream>>>(x, xb, trend);
    gemm_k<true><<<dim3(2176), dim3(256), 0, stream>>>(x, xb, wsb, dwb, trend, nullptr, bsum, out);
  } else {
    unsigned short* u = (unsigned short*)rest;
    unsigned short* v = (unsigned short*)(rest + UV_BYTES);
    prep_x<false><<<dim3(1024), dim3(256), 0, stream>>>(x, u, v);
    gemm_k<false><<<dim3(2176), dim3(256), 0, stream>>>(x, nullptr, wsb, dwb, u, v, bsum, out);
  }
  (void)in_sizes; (void)n_in; (void)out_size;
}